// Round 1
// baseline (471.799 us; speedup 1.0000x reference)
//
#include <hip/hip_runtime.h>

// ---------------------------------------------------------------------------
// GraphSAGE 2-layer forward (eval):
//   layer0: h1 = relu([self | mean10(neigh)] @ W0)  for 6 segments (src/dst/neg x lvl0/lvl1)
//   layer1: out = relu([h1_self | mean10(h1_neigh)] @ W1) for 3 segments
// Segments (rows): src0 256, src1 2560, dst0 256, dst1 2560, neg0 1280, neg1 12800
// ---------------------------------------------------------------------------

#define ROWS_TOT 19712  // 256+2560+256+2560+1280+12800

struct AggParams {
  const float* src[6];
  float* dst[6];
  long cum4[6];  // cumulative OUTPUT float4 counts, padded with total
};

// out[r, :] = mean over 10 consecutive input rows. D4 = row width in float4.
template <int D4>
__global__ __launch_bounds__(256) void agg_mean(AggParams P, long total4) {
  long idx = (long)blockIdx.x * blockDim.x + threadIdx.x;
  const long stride = (long)gridDim.x * blockDim.x;
  for (; idx < total4; idx += stride) {
    // branch-free job select (avoids scratch from dynamic kernel-arg indexing)
    const float* sp = P.src[0];
    float* dp = P.dst[0];
    long base = 0;
#pragma unroll
    for (int t = 1; t < 6; ++t) {
      const bool g = idx >= P.cum4[t - 1];
      sp = g ? P.src[t] : sp;
      dp = g ? P.dst[t] : dp;
      base = g ? P.cum4[t - 1] : base;
    }
    const long li = idx - base;
    const long r = li / D4;
    const int c = (int)(li - r * D4);
    const float4* s = (const float4*)sp + (r * 10) * (long)D4 + c;
    float4 acc = make_float4(0.f, 0.f, 0.f, 0.f);
#pragma unroll
    for (int k = 0; k < 10; ++k) {
      const float4 v = s[(long)k * D4];
      acc.x += v.x; acc.y += v.y; acc.z += v.z; acc.w += v.w;
    }
    acc.x *= 0.1f; acc.y *= 0.1f; acc.z *= 0.1f; acc.w *= 0.1f;
    ((float4*)dp)[r * (long)D4 + c] = acc;
  }
}

struct GemmSeg {
  const float* selfp;  // [m, KH]
  const float* meanp;  // [m, KH]
  float* outp;         // [m, N]
  int tile_end;        // cumulative 64-row tile count
};

struct GemmParams {
  GemmSeg seg[6];
  const float* W;  // [2*KH, N] row-major
  int nseg;
  int N;  // 256 (layer0) or 128 (layer1); also ldc and ldw
};

// C = relu([self | mean] @ W), 64x64 tile per block, 256 threads, 4x4 per thread.
template <int BK, int KH>
__global__ __launch_bounds__(256) void gemm_cat_relu(GemmParams P) {
  __shared__ float As[BK][68];  // transposed A tile: As[kk][row], pad 64->68 (16B-aligned rows)
  __shared__ float Bs[BK][64];

  const int tid = threadIdx.x;
  const int tx = tid & 15;
  const int ty = tid >> 4;
  const int N = P.N;

  // block-uniform segment lookup
  const int bt = blockIdx.x;
  int s = 0;
  while (s + 1 < P.nseg && bt >= P.seg[s].tile_end) ++s;
  const int tile0 = (s == 0) ? 0 : P.seg[s - 1].tile_end;
  const int row0 = (bt - tile0) * 64;
  const int n0 = blockIdx.y * 64;

  const float* Asrc[2] = {P.seg[s].selfp, P.seg[s].meanp};

  float acc[4][4] = {};

#pragma unroll
  for (int phase = 0; phase < 2; ++phase) {
    const float* __restrict__ A = Asrc[phase] + (long)row0 * KH;
    const float* __restrict__ Wp = P.W + (long)phase * KH * N + n0;
    for (int k0 = 0; k0 < KH; k0 += BK) {
      __syncthreads();
      // stage A tile (64 x BK) transposed into LDS
#pragma unroll
      for (int i = tid; i < 64 * BK; i += 256) {
        const int r = i / BK;
        const int kk = i - r * BK;
        As[kk][r] = A[(long)r * KH + (k0 + kk)];
      }
      // stage B tile (BK x 64)
#pragma unroll
      for (int i = tid; i < BK * 64; i += 256) {
        const int kk = i >> 6;
        const int nn = i & 63;
        Bs[kk][nn] = Wp[(long)(k0 + kk) * N + nn];
      }
      __syncthreads();
#pragma unroll
      for (int kk = 0; kk < BK; ++kk) {
        const float4 a = *(const float4*)&As[kk][ty * 4];
        const float4 b = *(const float4*)&Bs[kk][tx * 4];
        const float av[4] = {a.x, a.y, a.z, a.w};
        const float bv[4] = {b.x, b.y, b.z, b.w};
#pragma unroll
        for (int ii = 0; ii < 4; ++ii)
#pragma unroll
          for (int jj = 0; jj < 4; ++jj) acc[ii][jj] += av[ii] * bv[jj];
      }
    }
  }

  float* __restrict__ C = P.seg[s].outp;
#pragma unroll
  for (int ii = 0; ii < 4; ++ii) {
    const int r = row0 + ty * 4 + ii;
    float4 o;
    o.x = fmaxf(acc[ii][0], 0.f);
    o.y = fmaxf(acc[ii][1], 0.f);
    o.z = fmaxf(acc[ii][2], 0.f);
    o.w = fmaxf(acc[ii][3], 0.f);
    *(float4*)&C[(long)r * N + n0 + tx * 4] = o;
  }
}

extern "C" void kernel_launch(void* const* d_in, const int* in_sizes, int n_in,
                              void* d_out, int out_size, void* d_ws, size_t ws_size,
                              hipStream_t stream) {
  // setup_inputs() dict order: per i: x_src{i}, x_dst{i}, x_neg{i}; then W0, W1
  const float* xsrc0 = (const float*)d_in[0];
  const float* xdst0 = (const float*)d_in[1];
  const float* xneg0 = (const float*)d_in[2];
  const float* xsrc1 = (const float*)d_in[3];
  const float* xdst1 = (const float*)d_in[4];
  const float* xneg1 = (const float*)d_in[5];
  const float* xsrc2 = (const float*)d_in[6];
  const float* xdst2 = (const float*)d_in[7];
  const float* xneg2 = (const float*)d_in[8];
  const float* W0 = (const float*)d_in[9];
  const float* W1 = (const float*)d_in[10];
  float* out = (float*)d_out;

  // workspace layout (floats): M1 [19712 x 500] means, H1 [19712 x 256] layer0 out,
  // M2 [1792 x 256] layer1 means (reuses M1 region after layer0 GEMM).
  float* M1 = (float*)d_ws;
  float* H1 = M1 + (size_t)ROWS_TOT * 500;
  float* M2 = M1;

  static const int rows0[6] = {256, 2560, 256, 2560, 1280, 12800};

  // ---- layer0 aggregation: mean over 10 neighbors, d=500 ----
  {
    AggParams a0;
    const float* ns[6] = {xsrc1, xsrc2, xdst1, xdst2, xneg1, xneg2};
    long cum = 0;
    size_t roff = 0;
    for (int j = 0; j < 6; ++j) {
      a0.src[j] = ns[j];
      a0.dst[j] = M1 + roff * 500;
      cum += (long)rows0[j] * 125;
      a0.cum4[j] = cum;
      roff += rows0[j];
    }
    agg_mean<125><<<dim3(2048), dim3(256), 0, stream>>>(a0, cum);
  }

  // ---- layer0 GEMM: [19712, 1000] @ W0[1000,256] -> H1, relu ----
  {
    GemmParams g0;
    const float* selfs[6] = {xsrc0, xsrc1, xdst0, xdst1, xneg0, xneg1};
    int te = 0;
    size_t roff = 0;
    for (int j = 0; j < 6; ++j) {
      g0.seg[j].selfp = selfs[j];
      g0.seg[j].meanp = M1 + roff * 500;
      g0.seg[j].outp = H1 + roff * 256;
      te += rows0[j] / 64;
      g0.seg[j].tile_end = te;
      roff += rows0[j];
    }
    g0.W = W0;
    g0.nseg = 6;
    g0.N = 256;
    gemm_cat_relu<20, 500><<<dim3(308, 4), dim3(256), 0, stream>>>(g0);
  }

  // ---- layer1 aggregation: mean over 10 of H1 level-1 rows, d=256 ----
  {
    AggParams a1;
    a1.src[0] = H1 + (size_t)256 * 256;   // src lvl1 rows [256,2816)
    a1.dst[0] = M2;
    a1.src[1] = H1 + (size_t)3072 * 256;  // dst lvl1 rows [3072,5632)
    a1.dst[1] = M2 + (size_t)256 * 256;
    a1.src[2] = H1 + (size_t)6912 * 256;  // neg lvl1 rows [6912,19712)
    a1.dst[2] = M2 + (size_t)512 * 256;
    const long c0 = 256L * 64, c1 = c0 + 256L * 64, c2 = c1 + 1280L * 64;
    a1.cum4[0] = c0;
    a1.cum4[1] = c1;
    a1.cum4[2] = c2;
    for (int t = 3; t < 6; ++t) {
      a1.src[t] = a1.src[0];
      a1.dst[t] = a1.dst[0];
      a1.cum4[t] = c2;
    }
    agg_mean<64><<<dim3(448), dim3(256), 0, stream>>>(a1, c2);
  }

  // ---- layer1 GEMM: [1792, 512] @ W1[512,128] -> d_out, relu ----
  {
    GemmParams g1;
    g1.seg[0].selfp = H1;                      // src lvl0 h1
    g1.seg[0].meanp = M2;
    g1.seg[0].outp = out;
    g1.seg[0].tile_end = 4;
    g1.seg[1].selfp = H1 + (size_t)2816 * 256; // dst lvl0 h1
    g1.seg[1].meanp = M2 + (size_t)256 * 256;
    g1.seg[1].outp = out + (size_t)256 * 128;
    g1.seg[1].tile_end = 8;
    g1.seg[2].selfp = H1 + (size_t)5632 * 256; // neg lvl0 h1
    g1.seg[2].meanp = M2 + (size_t)512 * 256;
    g1.seg[2].outp = out + (size_t)512 * 128;
    g1.seg[2].tile_end = 28;
    for (int t = 3; t < 6; ++t) g1.seg[t] = g1.seg[2];
    g1.W = W1;
    g1.nseg = 3;
    g1.N = 128;
    gemm_cat_relu<16, 256><<<dim3(28, 2), dim3(256), 0, stream>>>(g1);
  }
}

// Round 2
// 149.163 us; speedup vs baseline: 3.1630x; 3.1630x over previous
//
#include <hip/hip_runtime.h>

// ---------------------------------------------------------------------------
// GraphSAGE 2-layer forward, bf16 MFMA path.
// Segment rows (in order): src0 256, src1 2560, dst0 256, dst1 2560, neg0 1280, neg1 12800
// H1 row offsets: src0@0 src1@256 dst0@2816 dst1@3072 neg0@5632 neg1@6912, total 19712
// ---------------------------------------------------------------------------

typedef __attribute__((ext_vector_type(8))) short bhalf8;
typedef __attribute__((ext_vector_type(4))) float floatx4;

__device__ __forceinline__ ushort f2bf(float f) {
  uint32_t u = __float_as_uint(f);
  return (ushort)((u + 0x7fffu + ((u >> 16) & 1u)) >> 16);
}
__device__ __forceinline__ float bf2f(ushort u) {
  return __uint_as_float(((uint32_t)u) << 16);
}

__device__ __forceinline__ void gll16(const void* g, void* l) {
  __builtin_amdgcn_global_load_lds((const __attribute__((address_space(1))) void*)g,
                                   (__attribute__((address_space(3))) void*)l, 16, 0, 0);
}

// ---------------- agg0: mean-10 + cast + pack into A1 [19712][1024] bf16 -----
struct Agg0P {
  const float* selfp[6];
  const float* neigh[6];
  long cum[6];     // cumulative items (rows*256)
  long outRow[6];  // A1 row offset
};

__global__ __launch_bounds__(256) void agg0_pack(Agg0P P, ushort* __restrict__ A1, long total) {
  const long stride = (long)gridDim.x * 256;
  for (long idx = (long)blockIdx.x * 256 + threadIdx.x; idx < total; idx += stride) {
    const float* sp = P.selfp[0];
    const float* np_ = P.neigh[0];
    long base = 0, orow = P.outRow[0];
#pragma unroll
    for (int t = 1; t < 6; ++t) {
      const bool g = idx >= P.cum[t - 1];
      sp = g ? P.selfp[t] : sp;
      np_ = g ? P.neigh[t] : np_;
      base = g ? P.cum[t - 1] : base;
      orow = g ? P.outRow[t] : orow;
    }
    const long li = idx - base;
    const long r = li >> 8;
    const int c = (int)(li & 255);
    ushort4 ov;
    if (c < 125) {  // self half: cols [0,500)
      const float4 v = ((const float4*)sp)[r * 125 + c];
      ov.x = f2bf(v.x); ov.y = f2bf(v.y); ov.z = f2bf(v.z); ov.w = f2bf(v.w);
    } else if (c < 250) {  // mean half: cols [500,1000)
      const int j = c - 125;
      const float4* b = (const float4*)np_ + r * 1250 + j;
      float ax = 0.f, ay = 0.f, az = 0.f, aw = 0.f;
#pragma unroll
      for (int k = 0; k < 10; ++k) {
        const float4 v = b[(long)k * 125];
        ax += v.x; ay += v.y; az += v.z; aw += v.w;
      }
      ov.x = f2bf(ax * 0.1f); ov.y = f2bf(ay * 0.1f);
      ov.z = f2bf(az * 0.1f); ov.w = f2bf(aw * 0.1f);
    } else {  // zero pad cols [1000,1024)
      ov.x = 0; ov.y = 0; ov.z = 0; ov.w = 0;
    }
    ((ushort4*)A1)[(orow + r) * 256 + c] = ov;
  }
}

// ---------------- W pack: [K][N] f32 -> [K/32][kg(4)][N][8] bf16 -------------
__global__ __launch_bounds__(256) void pack_w(const float* __restrict__ W0, const float* __restrict__ W1,
                                              ushort* __restrict__ W0p, ushort* __restrict__ W1p) {
  const int idx = blockIdx.x * 256 + threadIdx.x;  // exact grid: 1280*256 = 327680
  if (idx < 262144) {  // W0: K=1024 (orig 1000), N=256
    const int i = idx & 7, n = (idx >> 3) & 255, kg = (idx >> 11) & 3, kstp = idx >> 13;
    const int k = kstp * 32 + kg * 8 + i;
    const float v = (k < 1000) ? W0[k * 256 + n] : 0.f;
    W0p[idx] = f2bf(v);
  } else {  // W1: K=512, N=128
    const int j = idx - 262144;
    const int i = j & 7, n = (j >> 3) & 127, kg = (j >> 10) & 3, kstp = j >> 12;
    const int k = kstp * 32 + kg * 8 + i;
    W1p[j] = f2bf(W1[k * 128 + n]);
  }
}

// ---------------- agg1: H1 bf16 -> A2 [1792][512] bf16 (self | mean10) -------
__global__ __launch_bounds__(256) void agg1_pack(const ushort* __restrict__ H1, ushort* __restrict__ A2,
                                                 long total) {
  const long stride = (long)gridDim.x * 256;
  for (long idx = (long)blockIdx.x * 256 + threadIdx.x; idx < total; idx += stride) {
    const bool g1 = idx >= 32768, g2 = idx >= 65536;
    const long base = g2 ? 65536 : (g1 ? 32768 : 0);
    const int selfo = g2 ? 5632 : (g1 ? 2816 : 0);
    const int neigho = g2 ? 6912 : (g1 ? 3072 : 256);
    const int outo = g2 ? 512 : (g1 ? 256 : 0);
    const long li = idx - base;
    const long r = li >> 7;
    const int c = (int)(li & 127);
    const ushort4* H = (const ushort4*)H1;
    ushort4 ov;
    if (c < 64) {  // self: direct bf16 copy
      ov = H[((long)selfo + r) * 64 + c];
    } else {
      const int j = c - 64;
      float ax = 0.f, ay = 0.f, az = 0.f, aw = 0.f;
#pragma unroll
      for (int k = 0; k < 10; ++k) {
        const ushort4 v = H[((long)neigho + r * 10 + k) * 64 + j];
        ax += bf2f(v.x); ay += bf2f(v.y); az += bf2f(v.z); aw += bf2f(v.w);
      }
      ov.x = f2bf(ax * 0.1f); ov.y = f2bf(ay * 0.1f);
      ov.z = f2bf(az * 0.1f); ov.w = f2bf(aw * 0.1f);
    }
    ((ushort4*)A2)[((long)outo + r) * 128 + c] = ov;
  }
}

// ---------------- MFMA GEMM: C = relu(A[M,K]bf16 @ Bpacked[K,N]bf16) ---------
// BM x BN tile, 4 waves (2x2), each wave (MI*16)x(NI*16). BK=32.
// A staged via global_load_lds with XOR-swizzled source (slot ^= (row>>1)&3);
// B pre-packed fragment-linear [K/32][kg][N][8] -> linear LDS, conflict-free.
template <int BM, int BN, int MI, int NI, bool OUT_BF16>
__global__ __launch_bounds__(256) void gemm_mfma(const ushort* __restrict__ A,
                                                 const ushort* __restrict__ Bp,
                                                 void* __restrict__ Cout, int K, int Nfull) {
  __shared__ ushort As[BM * 32];      // BM rows x 32 bf16 (64B/row), kg-slot swizzled
  __shared__ ushort Bs[BN * 32];      // [kg(4)][n(BN)][8] bf16

  const int tid = threadIdx.x;
  const int wid = tid >> 6, l = tid & 63;
  const int wr = wid >> 1, wc = wid & 1;
  const int lr = l & 15, kg = l >> 4;
  const long row0 = (long)blockIdx.x * BM;
  const int n0 = blockIdx.y * BN;

  // LDS byte offsets for fragment reads (K-step invariant)
  int aoff[MI], boff[NI];
#pragma unroll
  for (int mi = 0; mi < MI; ++mi) {
    const int row = wr * (MI * 16) + mi * 16 + lr;
    aoff[mi] = row * 64 + ((kg ^ ((row >> 1) & 3)) << 4);
  }
#pragma unroll
  for (int ni = 0; ni < NI; ++ni) {
    const int cell = kg * BN + wc * (NI * 16) + ni * 16 + lr;
    boff[ni] = cell << 4;
  }

  floatx4 acc[MI][NI];
#pragma unroll
  for (int mi = 0; mi < MI; ++mi)
#pragma unroll
    for (int ni = 0; ni < NI; ++ni) acc[mi][ni] = (floatx4){0.f, 0.f, 0.f, 0.f};

  const int ksteps = K >> 5;
  for (int ks = 0; ks < ksteps; ++ks) {
    const int k0 = ks << 5;
    __syncthreads();
    // stage A tile (BM x 32 bf16), source pre-swizzled so swizzled ds_read is linear
#pragma unroll
    for (int it = 0; it < (BM * 64) / 4096; ++it) {
      const int o = it * 4096 + tid * 16;
      const int row = o >> 6;
      const int s = (o >> 4) & 3;
      const int kgs = s ^ ((row >> 1) & 3);
      const ushort* g = A + (row0 + row) * (size_t)K + (k0 + kgs * 8);
      gll16(g, (char*)As + it * 4096 + wid * 1024);
    }
    // stage B tile: 4*BN cells of 16B, fragment-linear
#pragma unroll
    for (int it = 0; it < (BN * 64) / 4096; ++it) {
      const int cell = it * 256 + tid;
      const int bkg = cell / BN;
      const int n = cell & (BN - 1);
      const ushort* g = Bp + ((size_t)(ks * 4 + bkg) * Nfull + (n0 + n)) * 8;
      gll16(g, (char*)Bs + it * 4096 + wid * 1024);
    }
    __syncthreads();

    bhalf8 af[MI], bf[NI];
#pragma unroll
    for (int mi = 0; mi < MI; ++mi) af[mi] = *(const bhalf8*)((const char*)As + aoff[mi]);
#pragma unroll
    for (int ni = 0; ni < NI; ++ni) bf[ni] = *(const bhalf8*)((const char*)Bs + boff[ni]);
#pragma unroll
    for (int mi = 0; mi < MI; ++mi)
#pragma unroll
      for (int ni = 0; ni < NI; ++ni)
        acc[mi][ni] = __builtin_amdgcn_mfma_f32_16x16x32_bf16(af[mi], bf[ni], acc[mi][ni], 0, 0, 0);
  }

  // epilogue: relu + store. C/D layout: col = lane&15, row = (lane>>4)*4 + reg
#pragma unroll
  for (int mi = 0; mi < MI; ++mi)
#pragma unroll
    for (int ni = 0; ni < NI; ++ni) {
      const floatx4 v = acc[mi][ni];
      const int gcol = n0 + wc * (NI * 16) + ni * 16 + lr;
#pragma unroll
      for (int r = 0; r < 4; ++r) {
        const long grow = row0 + wr * (MI * 16) + mi * 16 + kg * 4 + r;
        const float x = fmaxf(v[r], 0.f);
        if (OUT_BF16)
          ((ushort*)Cout)[grow * Nfull + gcol] = f2bf(x);
        else
          ((float*)Cout)[grow * Nfull + gcol] = x;
      }
    }
}

extern "C" void kernel_launch(void* const* d_in, const int* in_sizes, int n_in,
                              void* d_out, int out_size, void* d_ws, size_t ws_size,
                              hipStream_t stream) {
  const float* xsrc0 = (const float*)d_in[0];
  const float* xdst0 = (const float*)d_in[1];
  const float* xneg0 = (const float*)d_in[2];
  const float* xsrc1 = (const float*)d_in[3];
  const float* xdst1 = (const float*)d_in[4];
  const float* xneg1 = (const float*)d_in[5];
  const float* xsrc2 = (const float*)d_in[6];
  const float* xdst2 = (const float*)d_in[7];
  const float* xneg2 = (const float*)d_in[8];
  const float* W0 = (const float*)d_in[9];
  const float* W1 = (const float*)d_in[10];
  float* out = (float*)d_out;

  // workspace (ushorts), all 16B aligned:
  ushort* A1 = (ushort*)d_ws;            // 19712*1024 = 20,185,088
  ushort* H1 = A1 + 20185088;            // 19712*256  =  5,046,272
  ushort* A2 = H1 + 5046272;             // 1792*512   =    917,504
  ushort* W0p = A2 + 917504;             // 1024*256   =    262,144
  ushort* W1p = W0p + 262144;            // 512*128    =     65,536  (total ~53 MB)

  // ---- W pre-pack ----
  pack_w<<<dim3(1280), dim3(256), 0, stream>>>(W0, W1, W0p, W1p);

  // ---- layer0 agg + pack ----
  {
    Agg0P p;
    const float* selfs[6] = {xsrc0, xsrc1, xdst0, xdst1, xneg0, xneg1};
    const float* neighs[6] = {xsrc1, xsrc2, xdst1, xdst2, xneg1, xneg2};
    static const int rows[6] = {256, 2560, 256, 2560, 1280, 12800};
    long cum = 0, orow = 0;
    for (int j = 0; j < 6; ++j) {
      p.selfp[j] = selfs[j];
      p.neigh[j] = neighs[j];
      p.outRow[j] = orow;
      cum += (long)rows[j] * 256;
      p.cum[j] = cum;
      orow += rows[j];
    }
    agg0_pack<<<dim3(2048), dim3(256), 0, stream>>>(p, A1, cum);
  }

  // ---- layer0 GEMM: [19712,1024] @ [1024,256] -> H1 bf16 ----
  gemm_mfma<128, 128, 4, 4, true><<<dim3(154, 2), dim3(256), 0, stream>>>(A1, W0p, H1, 1024, 256);

  // ---- layer1 agg + pack: H1 -> A2 [1792][512] ----
  agg1_pack<<<dim3(896), dim3(256), 0, stream>>>(H1, A2, 229376);

  // ---- layer1 GEMM: [1792,512] @ [512,128] -> d_out fp32 ----
  gemm_mfma<64, 64, 2, 2, false><<<dim3(28, 2), dim3(256), 0, stream>>>(A2, W1p, out, 512, 128);
}

// Round 4
// 137.174 us; speedup vs baseline: 3.4394x; 1.0874x over previous
//
#include <hip/hip_runtime.h>

// ---------------------------------------------------------------------------
// GraphSAGE 2-layer forward, bf16 MFMA path.
// Segment rows (in order): src0 256, src1 2560, dst0 256, dst1 2560, neg0 1280, neg1 12800
// A1/H1 row offsets: src0@0 src1@256 dst0@2816 dst1@3072 neg0@5632 neg1@6912, total 19712
// ---------------------------------------------------------------------------

typedef __attribute__((ext_vector_type(8))) short bhalf8;
typedef __attribute__((ext_vector_type(4))) float floatx4;

__device__ __forceinline__ ushort f2bf(float f) {
  uint32_t u = __float_as_uint(f);
  return (ushort)((u + 0x7fffu + ((u >> 16) & 1u)) >> 16);
}
__device__ __forceinline__ float bf2f(ushort u) {
  return __uint_as_float(((uint32_t)u) << 16);
}

__device__ __forceinline__ void gll16(const void* g, void* l) {
  __builtin_amdgcn_global_load_lds((const __attribute__((address_space(1))) void*)g,
                                   (__attribute__((address_space(3))) void*)l, 16, 0, 0);
}

// ---------------- agg0: block-uniform self-cast / mean-reduce into A1 --------
// A1 is [19712][1024] bf16 = 256 ushort4/row: cols [0,125) self, [125,250) mean,
// [250,256) pad (pad written by pack_w kernel).
// Grid: 19250 blocks. b < 9625: self mode; else mean mode.
// Per-mode per-seg block counts {125,1250,125,1250,625,6250} (exact, no tails).
struct Agg0P {
  const float* selfp[6];
  const float* neigh[6];
  int blkEnd[6];  // cumulative blocks within a mode half: {125,1375,1500,2750,3375,9625}
  int outRow[6];  // {0,256,2816,3072,5632,6912}
};

__global__ __launch_bounds__(256) void agg0_split(Agg0P P, ushort* __restrict__ A1) {
  const int b = blockIdx.x;
  const bool mean_mode = b >= 9625;
  const int bb = mean_mode ? b - 9625 : b;
  int s = 0;
#pragma unroll
  for (int t = 0; t < 5; ++t) s = (bb >= P.blkEnd[t]) ? t + 1 : s;
  const int base = s ? P.blkEnd[s - 1] : 0;
  const int li = (bb - base) * 256 + threadIdx.x;
  const int r = li / 125;           // const-div -> magic mul
  const int j = li - r * 125;
  const long orow = (long)P.outRow[s] + r;
  ushort4 ov;
  if (!mean_mode) {
    const floatx4 v = ((const floatx4*)P.selfp[s])[(long)r * 125 + j];
    ov.x = f2bf(v.x); ov.y = f2bf(v.y); ov.z = f2bf(v.z); ov.w = f2bf(v.w);
    ((ushort4*)A1)[orow * 256 + j] = ov;
  } else {
    const floatx4* bsrc = (const floatx4*)P.neigh[s] + (long)r * 1250 + j;
    float ax = 0.f, ay = 0.f, az = 0.f, aw = 0.f;
#pragma unroll
    for (int k = 0; k < 10; ++k) {
      const floatx4 v = __builtin_nontemporal_load(bsrc + (long)k * 125);
      ax += v.x; ay += v.y; az += v.z; aw += v.w;
    }
    ov.x = f2bf(ax * 0.1f); ov.y = f2bf(ay * 0.1f);
    ov.z = f2bf(az * 0.1f); ov.w = f2bf(aw * 0.1f);
    ((ushort4*)A1)[orow * 256 + 125 + j] = ov;
  }
}

// ------- W pack + A1 pad-column zeroing.  Grid: 1742 blocks exact. ----------
// [0,262144): W0p  [K0=1024 pad from 1000][kg][n][8]
// [262144,327680): W1p  [K=512][kg][n][8]
// [327680,445952): A1 pad cols [250,256) ushort4 over 19712 rows
__global__ __launch_bounds__(256) void pack_w(const float* __restrict__ W0, const float* __restrict__ W1,
                                              ushort* __restrict__ W0p, ushort* __restrict__ W1p,
                                              ushort* __restrict__ A1) {
  const int idx = blockIdx.x * 256 + threadIdx.x;
  if (idx < 262144) {  // W0: K=1024 (orig 1000), N=256
    const int i = idx & 7, n = (idx >> 3) & 255, kg = (idx >> 11) & 3, kstp = idx >> 13;
    const int k = kstp * 32 + kg * 8 + i;
    const float v = (k < 1000) ? W0[k * 256 + n] : 0.f;
    W0p[idx] = f2bf(v);
  } else if (idx < 327680) {  // W1: K=512, N=128
    const int j = idx - 262144;
    const int i = j & 7, n = (j >> 3) & 127, kg = (j >> 10) & 3, kstp = j >> 12;
    const int k = kstp * 32 + kg * 8 + i;
    W1p[j] = f2bf(W1[k * 128 + n]);
  } else {  // A1 pad
    const int p = idx - 327680;       // < 118272
    const int r = p / 6;              // const-div
    const int sl = p - r * 6;
    ushort4 z; z.x = 0; z.y = 0; z.z = 0; z.w = 0;
    ((ushort4*)A1)[(long)r * 256 + 250 + sl] = z;
  }
}

// ---------------- agg1: H1 bf16 -> A2 [1792][512] bf16 (self | mean10) -------
__global__ __launch_bounds__(256) void agg1_pack(const ushort* __restrict__ H1, ushort* __restrict__ A2,
                                                 long total) {
  const long stride = (long)gridDim.x * 256;
  for (long idx = (long)blockIdx.x * 256 + threadIdx.x; idx < total; idx += stride) {
    const bool g1 = idx >= 32768, g2 = idx >= 65536;
    const long base = g2 ? 65536 : (g1 ? 32768 : 0);
    const int selfo = g2 ? 5632 : (g1 ? 2816 : 0);
    const int neigho = g2 ? 6912 : (g1 ? 3072 : 256);
    const int outo = g2 ? 512 : (g1 ? 256 : 0);
    const long li = idx - base;
    const long r = li >> 7;
    const int c = (int)(li & 127);
    const ushort4* H = (const ushort4*)H1;
    ushort4 ov;
    if (c < 64) {  // self: direct bf16 copy (wave-uniform: c-ranges align to waves)
      ov = H[((long)selfo + r) * 64 + c];
    } else {
      const int j = c - 64;
      float ax = 0.f, ay = 0.f, az = 0.f, aw = 0.f;
#pragma unroll
      for (int k = 0; k < 10; ++k) {
        const ushort4 v = H[((long)neigho + r * 10 + k) * 64 + j];
        ax += bf2f(v.x); ay += bf2f(v.y); az += bf2f(v.z); aw += bf2f(v.w);
      }
      ov.x = f2bf(ax * 0.1f); ov.y = f2bf(ay * 0.1f);
      ov.z = f2bf(az * 0.1f); ov.w = f2bf(aw * 0.1f);
    }
    ((ushort4*)A2)[((long)outo + r) * 128 + c] = ov;
  }
}

// ---------------- MFMA GEMM: C = relu(A[M,K]bf16 @ Bpacked[K,N]bf16) ---------
// BM x BN tile, 4 waves (2x2), each wave (MI*16)x(NI*16). BK=32.
// A staged via global_load_lds with XOR-swizzled source (slot ^= (row>>1)&3);
// B pre-packed fragment-linear [K/32][kg][N][8] -> linear LDS, conflict-free.
template <int BM, int BN, int MI, int NI, bool OUT_BF16>
__global__ __launch_bounds__(256) void gemm_mfma(const ushort* __restrict__ A,
                                                 const ushort* __restrict__ Bp,
                                                 void* __restrict__ Cout, int K, int Nfull) {
  __shared__ ushort As[BM * 32];      // BM rows x 32 bf16 (64B/row), kg-slot swizzled
  __shared__ ushort Bs[BN * 32];      // [kg(4)][n(BN)][8] bf16

  const int tid = threadIdx.x;
  const int wid = tid >> 6, l = tid & 63;
  const int wr = wid >> 1, wc = wid & 1;
  const int lr = l & 15, kg = l >> 4;
  const long row0 = (long)blockIdx.x * BM;
  const int n0 = blockIdx.y * BN;

  int aoff[MI], boff[NI];
#pragma unroll
  for (int mi = 0; mi < MI; ++mi) {
    const int row = wr * (MI * 16) + mi * 16 + lr;
    aoff[mi] = row * 64 + ((kg ^ ((row >> 1) & 3)) << 4);
  }
#pragma unroll
  for (int ni = 0; ni < NI; ++ni) {
    const int cell = kg * BN + wc * (NI * 16) + ni * 16 + lr;
    boff[ni] = cell << 4;
  }

  floatx4 acc[MI][NI];
#pragma unroll
  for (int mi = 0; mi < MI; ++mi)
#pragma unroll
    for (int ni = 0; ni < NI; ++ni) acc[mi][ni] = (floatx4){0.f, 0.f, 0.f, 0.f};

  const int ksteps = K >> 5;
  for (int ks = 0; ks < ksteps; ++ks) {
    const int k0 = ks << 5;
    __syncthreads();
#pragma unroll
    for (int it = 0; it < (BM * 64) / 4096; ++it) {
      const int o = it * 4096 + tid * 16;
      const int row = o >> 6;
      const int sw = (o >> 4) & 3;
      const int kgs = sw ^ ((row >> 1) & 3);
      const ushort* g = A + (row0 + row) * (size_t)K + (k0 + kgs * 8);
      gll16(g, (char*)As + it * 4096 + wid * 1024);
    }
#pragma unroll
    for (int it = 0; it < (BN * 64) / 4096; ++it) {
      const int cell = it * 256 + tid;
      const int bkg = cell / BN;
      const int n = cell & (BN - 1);
      const ushort* g = Bp + ((size_t)(ks * 4 + bkg) * Nfull + (n0 + n)) * 8;
      gll16(g, (char*)Bs + it * 4096 + wid * 1024);
    }
    __syncthreads();

    bhalf8 af[MI], bf[NI];
#pragma unroll
    for (int mi = 0; mi < MI; ++mi) af[mi] = *(const bhalf8*)((const char*)As + aoff[mi]);
#pragma unroll
    for (int ni = 0; ni < NI; ++ni) bf[ni] = *(const bhalf8*)((const char*)Bs + boff[ni]);
#pragma unroll
    for (int mi = 0; mi < MI; ++mi)
#pragma unroll
      for (int ni = 0; ni < NI; ++ni)
        acc[mi][ni] = __builtin_amdgcn_mfma_f32_16x16x32_bf16(af[mi], bf[ni], acc[mi][ni], 0, 0, 0);
  }

  // epilogue: relu + store. C/D layout: col = lane&15, row = (lane>>4)*4 + reg
#pragma unroll
  for (int mi = 0; mi < MI; ++mi)
#pragma unroll
    for (int ni = 0; ni < NI; ++ni) {
      const floatx4 v = acc[mi][ni];
      const int gcol = n0 + wc * (NI * 16) + ni * 16 + lr;
#pragma unroll
      for (int r = 0; r < 4; ++r) {
        const long grow = row0 + wr * (MI * 16) + mi * 16 + kg * 4 + r;
        const float x = fmaxf(v[r], 0.f);
        if (OUT_BF16)
          ((ushort*)Cout)[grow * Nfull + gcol] = f2bf(x);
        else
          ((float*)Cout)[grow * Nfull + gcol] = x;
      }
    }
}

extern "C" void kernel_launch(void* const* d_in, const int* in_sizes, int n_in,
                              void* d_out, int out_size, void* d_ws, size_t ws_size,
                              hipStream_t stream) {
  const float* xsrc0 = (const float*)d_in[0];
  const float* xdst0 = (const float*)d_in[1];
  const float* xneg0 = (const float*)d_in[2];
  const float* xsrc1 = (const float*)d_in[3];
  const float* xdst1 = (const float*)d_in[4];
  const float* xneg1 = (const float*)d_in[5];
  const float* xsrc2 = (const float*)d_in[6];
  const float* xdst2 = (const float*)d_in[7];
  const float* xneg2 = (const float*)d_in[8];
  const float* W0 = (const float*)d_in[9];
  const float* W1 = (const float*)d_in[10];
  float* out = (float*)d_out;

  // workspace (ushorts), all 16B aligned:
  ushort* A1 = (ushort*)d_ws;            // 19712*1024 = 20,185,088
  ushort* H1 = A1 + 20185088;            // 19712*256  =  5,046,272
  ushort* A2 = H1 + 5046272;             // 1792*512   =    917,504
  ushort* W0p = A2 + 917504;             // 1024*256   =    262,144
  ushort* W1p = W0p + 262144;            // 512*128    =     65,536  (total ~53 MB)

  // ---- W pre-pack + A1 pad zero ----
  pack_w<<<dim3(1742), dim3(256), 0, stream>>>(W0, W1, W0p, W1p, A1);

  // ---- layer0 agg: block-uniform self/mean split ----
  {
    Agg0P p;
    const float* selfs[6] = {xsrc0, xsrc1, xdst0, xdst1, xneg0, xneg1};
    const float* neighs[6] = {xsrc1, xsrc2, xdst1, xdst2, xneg1, xneg2};
    static const int rows[6] = {256, 2560, 256, 2560, 1280, 12800};
    int cumb = 0, orow = 0;
    for (int j = 0; j < 6; ++j) {
      p.selfp[j] = selfs[j];
      p.neigh[j] = neighs[j];
      cumb += rows[j] * 125 / 256;
      p.blkEnd[j] = cumb;   // {125,1375,1500,2750,3375,9625}
      p.outRow[j] = orow;
      orow += rows[j];
    }
    agg0_split<<<dim3(19250), dim3(256), 0, stream>>>(p, A1);
  }

  // ---- layer0 GEMM: [19712,1024] @ [1024,256] -> H1 bf16 ----
  gemm_mfma<128, 128, 4, 4, true><<<dim3(154, 2), dim3(256), 0, stream>>>(A1, W0p, H1, 1024, 256);

  // ---- layer1 agg + pack: H1 -> A2 [1792][512] ----
  agg1_pack<<<dim3(896), dim3(256), 0, stream>>>(H1, A2, 229376);

  // ---- layer1 GEMM: [1792,512] @ [512,128] -> d_out fp32 ----
  gemm_mfma<64, 64, 2, 2, false><<<dim3(28, 2), dim3(256), 0, stream>>>(A2, W1p, out, 512, 128);
}